// Round 11
// baseline (395.665 us; speedup 1.0000x reference)
//
#include <hip/hip_runtime.h>
#include <hip/hip_fp16.h>

static constexpr int NN = 100000;
static constexpr int NE = 3200000;
static constexpr int NG = 512;
static constexpr int NCB = 196;                       // coarse bins: 512 nodes (dst>>9)
static constexpr int CHK = 8192;
static constexpr int NCH = (NE + CHK - 1) / CHK;      // 391 chunks
static constexpr int NCNT = NCB * NCH;                // 76636 count cells
static constexpr int SCAN_BLK = 2048;
static constexpr int NSB = (NCNT + SCAN_BLK - 1) / SCAN_BLK;  // 38

// ---- fp8 e4m3 pack/unpack via gfx950 hardware converts ---------------------
typedef float f32x2 __attribute__((ext_vector_type(2)));

__device__ __forceinline__ void acc_fp8x4(unsigned v, float* a) {
    f32x2 lo = __builtin_amdgcn_cvt_pk_f32_fp8((int)v, false);
    f32x2 hi = __builtin_amdgcn_cvt_pk_f32_fp8((int)v, true);
    a[0] += lo.x; a[1] += lo.y; a[2] += hi.x; a[3] += hi.y;
}
__device__ __forceinline__ void set_fp8x4(unsigned v, float* a) {
    f32x2 lo = __builtin_amdgcn_cvt_pk_f32_fp8((int)v, false);
    f32x2 hi = __builtin_amdgcn_cvt_pk_f32_fp8((int)v, true);
    a[0] = lo.x; a[1] = lo.y; a[2] = hi.x; a[3] = hi.y;
}
__device__ __forceinline__ unsigned pack_fp8x4(float a, float b, float c, float d) {
    int p = __builtin_amdgcn_cvt_pk_fp8_f32(a, b, 0, false);
    p = __builtin_amdgcn_cvt_pk_fp8_f32(c, d, p, true);
    return (unsigned)p;
}

// ---- per-chunk coarse histogram: cntC[bin*NCH + chunk] ---------------------
__global__ __launch_bounds__(256) void k_histC(const int* __restrict__ dst,
                                               int* __restrict__ cntC, int e) {
    __shared__ int h[NCB];
    for (int i = threadIdx.x; i < NCB; i += 256) h[i] = 0;
    __syncthreads();
    const int s = blockIdx.x * CHK, eend = min(s + CHK, e);
    for (int i = s + threadIdx.x; i < eend; i += 256)
        atomicAdd(&h[dst[i] >> 9], 1);
    __syncthreads();
    for (int i = threadIdx.x; i < NCB; i += 256)
        cntC[(size_t)i * NCH + blockIdx.x] = h[i];
}

// ---- 2-kernel exclusive scan (block-local + bsum scan; add folded later) ---
__global__ __launch_bounds__(256) void k_scanA(const int* __restrict__ in,
                                               int* __restrict__ out,
                                               int* __restrict__ bsum, int n) {
    __shared__ int s[256];
    const int tid = threadIdx.x;
    const int base = blockIdx.x * SCAN_BLK + tid * 8;
    int v[8], t = 0;
#pragma unroll
    for (int c = 0; c < 8; c++) {
        int idx = base + c;
        v[c] = (idx < n) ? in[idx] : 0;
        t += v[c];
    }
    s[tid] = t;
    __syncthreads();
    for (int off = 1; off < 256; off <<= 1) {
        int x = (tid >= off) ? s[tid - off] : 0;
        __syncthreads();
        s[tid] += x;
        __syncthreads();
    }
    if (tid == 255) bsum[blockIdx.x] = s[255];
    int run = s[tid] - t;
#pragma unroll
    for (int c = 0; c < 8; c++) {
        int idx = base + c;
        if (idx < n) out[idx] = run;
        run += v[c];
    }
}

__global__ __launch_bounds__(256) void k_scanB(int* __restrict__ bsum, int nb) {
    __shared__ int s[256];
    const int tid = threadIdx.x;
    int v = (tid < nb) ? bsum[tid] : 0;
    s[tid] = v;
    __syncthreads();
    for (int off = 1; off < 256; off <<= 1) {
        int x = (tid >= off) ? s[tid - off] : 0;
        __syncthreads();
        s[tid] += x;
        __syncthreads();
    }
    if (tid < nb) bsum[tid] = s[tid] - v;
}

// ---- coarse scatter: tmp[pos] = (dst&511)<<17 | src  (26 bits) -------------
// global offset = sc[idx] + bsum[idx>>11]  (scanC folded in)
__global__ __launch_bounds__(256) void k_scatC(const int* __restrict__ src,
                                               const int* __restrict__ dst,
                                               const int* __restrict__ sc,
                                               const int* __restrict__ bsum,
                                               unsigned* __restrict__ tmp, int e) {
    __shared__ int cur[NCB];
    for (int i = threadIdx.x; i < NCB; i += 256) {
        size_t idx = (size_t)i * NCH + blockIdx.x;
        cur[i] = sc[idx] + bsum[idx >> 11];
    }
    __syncthreads();
    const int s = blockIdx.x * CHK, eend = min(s + CHK, e);
    for (int i = s + threadIdx.x; i < eend; i += 256) {
        int d = dst[i];
        int p = atomicAdd(&cur[d >> 9], 1);
        tmp[p] = ((unsigned)(d & 511) << 17) | (unsigned)src[i];
    }
}

// ---- per-bin (512 nodes): LDS hist + scan; emit degi/offs/dis + csr --------
__global__ __launch_bounds__(1024) void k_fill512(const unsigned* __restrict__ tmp,
                                                  const int* __restrict__ sc,
                                                  const int* __restrict__ bsum,
                                                  int* __restrict__ csr,
                                                  int* __restrict__ degi,
                                                  int* __restrict__ offs,
                                                  float* __restrict__ dis,
                                                  int n, int etotal) {
    __shared__ int cnt[512];
    __shared__ int s[512];
    __shared__ int cur[512];
    const int b = blockIdx.x, tid = threadIdx.x;
    if (tid < 512) cnt[tid] = 0;
    size_t i0 = (size_t)b * NCH;
    const int e0 = sc[i0] + bsum[i0 >> 11];
    int e1 = etotal;
    if (b + 1 < NCB) {
        size_t i1 = (size_t)(b + 1) * NCH;
        e1 = sc[i1] + bsum[i1 >> 11];
    }
    __syncthreads();
    for (int e = e0 + tid; e < e1; e += 1024)
        atomicAdd(&cnt[tmp[e] >> 17], 1);
    __syncthreads();
    int v = 0;
    if (tid < 512) { v = cnt[tid]; s[tid] = v; }
    __syncthreads();
    for (int off = 1; off < 512; off <<= 1) {
        int x = 0;
        if (tid < 512 && tid >= off) x = s[tid - off];
        __syncthreads();
        if (tid < 512) s[tid] += x;
        __syncthreads();
    }
    if (tid < 512) {
        int c = e0 + s[tid] - v;   // exclusive prefix within bin window
        cur[tid] = c;
        int node = b * 512 + tid;
        if (node < n) {
            degi[node] = v;
            offs[node] = c;
            dis[node] = rsqrtf((float)v + 1.0f);
        }
    }
    __syncthreads();
    for (int e = e0 + tid; e < e1; e += 1024) {
        unsigned pk = tmp[e];
        int p = atomicAdd(&cur[pk >> 17], 1);
        csr[p] = (int)(pk & 0x1FFFFu);
    }
}

// ---- gemm1: H1' = fp8((x @ W1) * dis[row])  (128 -> 32) --------------------
__global__ __launch_bounds__(256) void k_gemm1(const float* __restrict__ X,
                                               const float* __restrict__ W,
                                               const float* __restrict__ dis,
                                               unsigned* __restrict__ H, int n) {
    constexpr int IN = 128, ROWS = 32;
    __shared__ float sW[IN * 32];
    __shared__ float sX[ROWS][IN];
    const int tid = threadIdx.x;
    for (int i = tid; i < IN * 32; i += 256) sW[i] = W[i];
    const int row0 = blockIdx.x * ROWS;
    const float4* X4 = (const float4*)X;
    for (int i = tid; i < ROWS * 32; i += 256) {
        int r = row0 + (i >> 5);
        float4 v = make_float4(0.f, 0.f, 0.f, 0.f);
        if (r < n) v = X4[(size_t)r * 32 + (i & 31)];
        ((float4*)&sX[i >> 5][0])[i & 31] = v;
    }
    __syncthreads();
    const int lr = tid >> 3;        // local row
    const int cg = tid & 7;         // col group (4 cols)
    const int gr = row0 + lr;
    float acc[4] = {0.f, 0.f, 0.f, 0.f};
#pragma unroll 8
    for (int k = 0; k < IN; k++) {
        float xv = sX[lr][k];
#pragma unroll
        for (int c = 0; c < 4; c++)
            acc[c] = fmaf(xv, sW[k * 32 + 4 * cg + c], acc[c]);
    }
    if (gr < n) {
        float dd = dis[gr];
        H[(size_t)gr * 8 + cg] =
            pack_fp8x4(acc[0] * dd, acc[1] * dd, acc[2] * dd, acc[3] * dd);
    }
}

// ---- layer-1 pull (32-dim fp8): 8 lanes/node, 8-edge unroll, NT csr --------
// out = fp8(relu(dis*(self+sum)+b) * dis)
__global__ __launch_bounds__(256) void k_pull2(
        const unsigned* __restrict__ Hp, const int* __restrict__ offs,
        const int* __restrict__ degi, const int* __restrict__ csr,
        const float* __restrict__ dis, const float* __restrict__ b,
        unsigned* __restrict__ A, int n) {
    const int group = threadIdx.x >> 3, j0 = threadIdx.x & 7;
    const int d = blockIdx.x * 32 + group;
    if (d >= n) return;
    float acc[4];
    set_fp8x4(Hp[(size_t)d * 8 + j0], acc);
    int e = offs[d];
    const int end = e + degi[d];
    for (; e + 7 < end; e += 8) {
        unsigned v0 = Hp[(size_t)__builtin_nontemporal_load(csr + e) * 8 + j0];
        unsigned v1 = Hp[(size_t)__builtin_nontemporal_load(csr + e + 1) * 8 + j0];
        unsigned v2 = Hp[(size_t)__builtin_nontemporal_load(csr + e + 2) * 8 + j0];
        unsigned v3 = Hp[(size_t)__builtin_nontemporal_load(csr + e + 3) * 8 + j0];
        unsigned v4 = Hp[(size_t)__builtin_nontemporal_load(csr + e + 4) * 8 + j0];
        unsigned v5 = Hp[(size_t)__builtin_nontemporal_load(csr + e + 5) * 8 + j0];
        unsigned v6 = Hp[(size_t)__builtin_nontemporal_load(csr + e + 6) * 8 + j0];
        unsigned v7 = Hp[(size_t)__builtin_nontemporal_load(csr + e + 7) * 8 + j0];
        acc_fp8x4(v0, acc); acc_fp8x4(v1, acc);
        acc_fp8x4(v2, acc); acc_fp8x4(v3, acc);
        acc_fp8x4(v4, acc); acc_fp8x4(v5, acc);
        acc_fp8x4(v6, acc); acc_fp8x4(v7, acc);
    }
    for (; e < end; e++)
        acc_fp8x4(Hp[(size_t)__builtin_nontemporal_load(csr + e) * 8 + j0], acc);
    const float dd = dis[d];
    float r[4];
#pragma unroll
    for (int c = 0; c < 4; c++)
        r[c] = fmaxf(fmaf(acc[c], dd, b[4 * j0 + c]), 0.f) * dd;
    A[(size_t)d * 8 + j0] = pack_fp8x4(r[0], r[1], r[2], r[3]);
}

// ---- layer-2: pull(32 fp8) + fused gemm 32->48 -> fp8 padded-64 rows -------
__global__ __launch_bounds__(256) void k_pullmm32(
        const unsigned* __restrict__ Hp, const int* __restrict__ offs,
        const int* __restrict__ degi, const int* __restrict__ csr,
        const float* __restrict__ dis, const float* __restrict__ W,
        const float* __restrict__ b, unsigned* __restrict__ A, int n) {
    __shared__ float sW[32 * 48];
    __shared__ float rows[32][33];   // +1 pad: kill 8-way store conflict
    for (int i = threadIdx.x; i < 32 * 48; i += 256) sW[i] = W[i];
    const int group = threadIdx.x >> 3, j0 = threadIdx.x & 7;
    const int d = blockIdx.x * 32 + group;
    if (d < n) {
        float acc[4];
        set_fp8x4(Hp[(size_t)d * 8 + j0], acc);
        int e = offs[d];
        const int end = e + degi[d];
        for (; e + 7 < end; e += 8) {
            unsigned v0 = Hp[(size_t)__builtin_nontemporal_load(csr + e) * 8 + j0];
            unsigned v1 = Hp[(size_t)__builtin_nontemporal_load(csr + e + 1) * 8 + j0];
            unsigned v2 = Hp[(size_t)__builtin_nontemporal_load(csr + e + 2) * 8 + j0];
            unsigned v3 = Hp[(size_t)__builtin_nontemporal_load(csr + e + 3) * 8 + j0];
            unsigned v4 = Hp[(size_t)__builtin_nontemporal_load(csr + e + 4) * 8 + j0];
            unsigned v5 = Hp[(size_t)__builtin_nontemporal_load(csr + e + 5) * 8 + j0];
            unsigned v6 = Hp[(size_t)__builtin_nontemporal_load(csr + e + 6) * 8 + j0];
            unsigned v7 = Hp[(size_t)__builtin_nontemporal_load(csr + e + 7) * 8 + j0];
            acc_fp8x4(v0, acc); acc_fp8x4(v1, acc);
            acc_fp8x4(v2, acc); acc_fp8x4(v3, acc);
            acc_fp8x4(v4, acc); acc_fp8x4(v5, acc);
            acc_fp8x4(v6, acc); acc_fp8x4(v7, acc);
        }
        for (; e < end; e++)
            acc_fp8x4(Hp[(size_t)__builtin_nontemporal_load(csr + e) * 8 + j0], acc);
        const float dd = dis[d];
#pragma unroll
        for (int c = 0; c < 4; c++) rows[group][4 * j0 + c] = acc[c] * dd;
    }
    __syncthreads();
    const int row0 = blockIdx.x * 32;
    // 32 rows x 16 uint-groups (12 real + 4 pad): compute 4 cols + pack inline
    for (int u = threadIdx.x; u < 32 * 16; u += 256) {
        int nl = u >> 4, cg = u & 15;
        int gr = row0 + nl;
        if (gr < n) {
            unsigned p = 0;
            if (cg < 12) {
                float dd2 = dis[gr];
                float r[4];
#pragma unroll
                for (int c = 0; c < 4; c++) {
                    float s = b[4 * cg + c];
#pragma unroll
                    for (int k = 0; k < 32; k++)
                        s = fmaf(rows[nl][k], sW[k * 48 + 4 * cg + c], s);
                    r[c] = fmaxf(s, 0.f) * dd2;
                }
                p = pack_fp8x4(r[0], r[1], r[2], r[3]);
            }
            A[(size_t)gr * 16 + cg] = p;
        }
    }
}

// ---- layer-3: pull(48 fp8, 64B rows) + fused gemm 48->64 -> A3 fp16 --------
__global__ __launch_bounds__(256) void k_pullmm48(
        const uint2* __restrict__ Hp, const int* __restrict__ offs,
        const int* __restrict__ degi, const int* __restrict__ csr,
        const float* __restrict__ dis, const float* __restrict__ W,
        const float* __restrict__ b, __half* __restrict__ A, int n) {
    __shared__ float sW[48 * 64];
    __shared__ float rows[32][50];   // stride 50: spread store banks
    for (int i = threadIdx.x; i < 48 * 64; i += 256) sW[i] = W[i];
    const int group = threadIdx.x >> 3, j0 = threadIdx.x & 7;
    const int d = blockIdx.x * 32 + group;
    if (d < n) {
        float acc[8];
        uint2 sv = Hp[(size_t)d * 8 + j0];
        set_fp8x4(sv.x, acc); set_fp8x4(sv.y, acc + 4);
        int e = offs[d];
        const int end = e + degi[d];
        for (; e + 7 < end; e += 8) {
            uint2 v0 = Hp[(size_t)__builtin_nontemporal_load(csr + e) * 8 + j0];
            uint2 v1 = Hp[(size_t)__builtin_nontemporal_load(csr + e + 1) * 8 + j0];
            uint2 v2 = Hp[(size_t)__builtin_nontemporal_load(csr + e + 2) * 8 + j0];
            uint2 v3 = Hp[(size_t)__builtin_nontemporal_load(csr + e + 3) * 8 + j0];
            uint2 v4 = Hp[(size_t)__builtin_nontemporal_load(csr + e + 4) * 8 + j0];
            uint2 v5 = Hp[(size_t)__builtin_nontemporal_load(csr + e + 5) * 8 + j0];
            uint2 v6 = Hp[(size_t)__builtin_nontemporal_load(csr + e + 6) * 8 + j0];
            uint2 v7 = Hp[(size_t)__builtin_nontemporal_load(csr + e + 7) * 8 + j0];
            acc_fp8x4(v0.x, acc); acc_fp8x4(v0.y, acc + 4);
            acc_fp8x4(v1.x, acc); acc_fp8x4(v1.y, acc + 4);
            acc_fp8x4(v2.x, acc); acc_fp8x4(v2.y, acc + 4);
            acc_fp8x4(v3.x, acc); acc_fp8x4(v3.y, acc + 4);
            acc_fp8x4(v4.x, acc); acc_fp8x4(v4.y, acc + 4);
            acc_fp8x4(v5.x, acc); acc_fp8x4(v5.y, acc + 4);
            acc_fp8x4(v6.x, acc); acc_fp8x4(v6.y, acc + 4);
            acc_fp8x4(v7.x, acc); acc_fp8x4(v7.y, acc + 4);
        }
        for (; e < end; e++) {
            uint2 v = Hp[(size_t)__builtin_nontemporal_load(csr + e) * 8 + j0];
            acc_fp8x4(v.x, acc); acc_fp8x4(v.y, acc + 4);
        }
        const float dd = dis[d];
        if (j0 < 6) {   // j0>=6 holds pad bytes 48..63
#pragma unroll
            for (int c = 0; c < 8; c++) rows[group][8 * j0 + c] = acc[c] * dd;
        }
    }
    __syncthreads();
    const int row0 = blockIdx.x * 32;
#pragma unroll
    for (int o = 0; o < 8; o++) {
        int idx = o * 256 + threadIdx.x;
        int nl = idx >> 6, col = idx & 63;
        int gr = row0 + nl;
        if (gr < n) {
            float s = b[col];
#pragma unroll
            for (int k = 0; k < 48; k++)
                s = fmaf(rows[nl][k], sW[k * 64 + col], s);
            A[(size_t)gr * 64 + col] = __float2half(s);
        }
    }
}

// ---- fused: graph bounds (binary search) + mean-pool + MLP head + softmax --
__global__ __launch_bounds__(256) void k_poolhead(
        const __half* __restrict__ A3, const int* __restrict__ batch,
        const float* __restrict__ f1w, const float* __restrict__ f1b,
        const float* __restrict__ f2w, const float* __restrict__ f2b,
        float* __restrict__ out, int n, int ngr) {
    const int g = blockIdx.x;
    __shared__ int sb[2];
    if (threadIdx.x < 2) {
        int target = g + threadIdx.x;
        int lo = 0, hi = n;
        while (lo < hi) {
            int mid = (lo + hi) >> 1;
            if (batch[mid] < target) lo = mid + 1; else hi = mid;
        }
        sb[threadIdx.x] = lo;
    }
    __syncthreads();
    const int s = sb[0], e = sb[1];
    const int j = threadIdx.x & 63, rl = threadIdx.x >> 6;
    float sum = 0.f;
    for (int node = s + rl; node < e; node += 4)
        sum += fmaxf(__half2float(A3[(size_t)node * 64 + j]), 0.f);
    __shared__ float red[4][64];
    __shared__ float p[64], z[32], lg[16];
    red[rl][j] = sum;
    __syncthreads();
    if (rl == 0)
        p[j] = (red[0][j] + red[1][j] + red[2][j] + red[3][j]) /
               fmaxf((float)(e - s), 1.f);
    __syncthreads();
    const int t = threadIdx.x;
    if (t < 32) {
        float acc = f1b[t];
        for (int k = 0; k < 64; k++) acc = fmaf(p[k], f1w[k * 32 + t], acc);
        z[t] = fmaxf(acc, 0.f);
    }
    __syncthreads();
    if (t < 16) {
        float acc = f2b[t];
        for (int k = 0; k < 32; k++) acc = fmaf(z[k], f2w[k * 16 + t], acc);
        lg[t] = acc;
    }
    __syncthreads();
    if (t < 16) {
        float m = lg[0];
        for (int i = 1; i < 16; i++) m = fmaxf(m, lg[i]);
        float sden = 0.f;
        for (int i = 0; i < 16; i++) sden += expf(lg[i] - m);
        out[g * 16 + t] = expf(lg[t] - m) / sden;
    }
}

extern "C" void kernel_launch(void* const* d_in, const int* in_sizes, int n_in,
                              void* d_out, int out_size, void* d_ws, size_t ws_size,
                              hipStream_t stream) {
    (void)in_sizes; (void)n_in; (void)out_size; (void)ws_size;
    const float* x     = (const float*)d_in[0];
    const int*   ei    = (const int*)d_in[1];
    const int*   batch = (const int*)d_in[2];
    const float* W1 = (const float*)d_in[3];
    const float* b1 = (const float*)d_in[4];
    const float* W2 = (const float*)d_in[5];  const float* b2 = (const float*)d_in[6];
    const float* W3 = (const float*)d_in[7];  const float* b3 = (const float*)d_in[8];
    const float* f1w = (const float*)d_in[9]; const float* f1b = (const float*)d_in[10];
    const float* f2w = (const float*)d_in[11];const float* f2b = (const float*)d_in[12];
    float* out = (float*)d_out;

    const int* src = ei;
    const int* dst = ei + NE;

    // Workspace (~41 MB):
    //   tmp uint[NE] (12.8MB)  aliased with  A3 fp16[NN*64] (12.8MB)
    //   H1 fp8[NN*32] (3.2MB), H2 fp8[NN*32] (3.2MB), H3 fp8[NN*64] (6.4MB)
    float* ws = (float*)d_ws;
    size_t o = 0;
    float* dis    = ws + o; o += NN;
    int*   degi   = (int*)(ws + o); o += NN;
    int*   offs   = (int*)(ws + o); o += NN;
    int*   cntC   = (int*)(ws + o); o += 76640;       // NCNT padded to /16
    int*   sc     = (int*)(ws + o); o += 76640;
    int*   bsum   = (int*)(ws + o); o += 48;
    int*   csr    = (int*)(ws + o); o += NE;
    unsigned* TA  = (unsigned*)(ws + o); o += NE;     // tmp | A3
    unsigned* H1  = (unsigned*)(ws + o); o += NN * 8;
    unsigned* H2  = (unsigned*)(ws + o); o += NN * 8;
    unsigned* H3  = (unsigned*)(ws + o); o += NN * 16;

    unsigned* tmp = TA;
    __half*   A3  = (__half*)TA;

    // CSR build: coarse counting sort (196 bins x 512 nodes) + in-LDS sub-sort
    k_histC<<<NCH, 256, 0, stream>>>(dst, cntC, NE);
    k_scanA<<<NSB, 256, 0, stream>>>(cntC, sc, bsum, NCNT);
    k_scanB<<<1, 256, 0, stream>>>(bsum, NSB);
    k_scatC<<<NCH, 256, 0, stream>>>(src, dst, sc, bsum, tmp, NE);
    k_fill512<<<NCB, 1024, 0, stream>>>(tmp, sc, bsum, csr, degi, offs, dis, NN, NE);

    const int PGRID = (NN + 31) / 32;  // 3125

    // Layer 1: transform-first GEMM (128->32) -> fp8 H1; pull -> fp8 H2
    k_gemm1<<<(NN + 31) / 32, 256, 0, stream>>>(x, W1, dis, H1, NN);
    k_pull2<<<PGRID, 256, 0, stream>>>(H1, offs, degi, csr, dis, b1, H2, NN);

    // Layer 2: pull(32 fp8) + fused gemm 32->48 -> fp8 H3 (64B rows)
    k_pullmm32<<<PGRID, 256, 0, stream>>>(H2, offs, degi, csr, dis, W2, b2, H3, NN);

    // Layer 3: pull(48 fp8) + fused gemm 48->64 -> A3 fp16
    k_pullmm48<<<PGRID, 256, 0, stream>>>(
        (const uint2*)H3, offs, degi, csr, dis, W3, b3, A3, NN);

    // Fused bounds + pool + head
    k_poolhead<<<NG, 256, 0, stream>>>(A3, batch, f1w, f1b, f2w, f2b, out, NN, NG);
}

// Round 12
// 367.507 us; speedup vs baseline: 1.0766x; 1.0766x over previous
//
#include <hip/hip_runtime.h>
#include <hip/hip_fp16.h>

static constexpr int NN = 100000;
static constexpr int NE = 3200000;
static constexpr int NG = 512;
static constexpr int NCB = 196;                       // coarse bins: 512 nodes (dst>>9)
static constexpr int CHK = 8192;
static constexpr int NCH = (NE + CHK - 1) / CHK;      // 391 chunks
static constexpr int NCNT = NCB * NCH;                // 76636 count cells
static constexpr int SCAN_BLK = 2048;
static constexpr int NSB = (NCNT + SCAN_BLK - 1) / SCAN_BLK;  // 38

// ---- fp8 e4m3 pack/unpack via gfx950 hardware converts ---------------------
typedef float f32x2 __attribute__((ext_vector_type(2)));

__device__ __forceinline__ void acc_fp8x4(unsigned v, float* a) {
    f32x2 lo = __builtin_amdgcn_cvt_pk_f32_fp8((int)v, false);
    f32x2 hi = __builtin_amdgcn_cvt_pk_f32_fp8((int)v, true);
    a[0] += lo.x; a[1] += lo.y; a[2] += hi.x; a[3] += hi.y;
}
__device__ __forceinline__ void set_fp8x4(unsigned v, float* a) {
    f32x2 lo = __builtin_amdgcn_cvt_pk_f32_fp8((int)v, false);
    f32x2 hi = __builtin_amdgcn_cvt_pk_f32_fp8((int)v, true);
    a[0] = lo.x; a[1] = lo.y; a[2] = hi.x; a[3] = hi.y;
}
__device__ __forceinline__ unsigned pack_fp8x4(float a, float b, float c, float d) {
    int p = __builtin_amdgcn_cvt_pk_fp8_f32(a, b, 0, false);
    p = __builtin_amdgcn_cvt_pk_fp8_f32(c, d, p, true);
    return (unsigned)p;
}

// ---- per-chunk coarse histogram: cntC[bin*NCH + chunk] ---------------------
__global__ __launch_bounds__(256) void k_histC(const int* __restrict__ dst,
                                               int* __restrict__ cntC, int e) {
    __shared__ int h[NCB];
    for (int i = threadIdx.x; i < NCB; i += 256) h[i] = 0;
    __syncthreads();
    const int s = blockIdx.x * CHK, eend = min(s + CHK, e);
    for (int i = s + threadIdx.x; i < eend; i += 256)
        atomicAdd(&h[dst[i] >> 9], 1);
    __syncthreads();
    for (int i = threadIdx.x; i < NCB; i += 256)
        cntC[(size_t)i * NCH + blockIdx.x] = h[i];
}

// ---- 2-kernel exclusive scan (block-local + bsum scan; add folded later) ---
__global__ __launch_bounds__(256) void k_scanA(const int* __restrict__ in,
                                               int* __restrict__ out,
                                               int* __restrict__ bsum, int n) {
    __shared__ int s[256];
    const int tid = threadIdx.x;
    const int base = blockIdx.x * SCAN_BLK + tid * 8;
    int v[8], t = 0;
#pragma unroll
    for (int c = 0; c < 8; c++) {
        int idx = base + c;
        v[c] = (idx < n) ? in[idx] : 0;
        t += v[c];
    }
    s[tid] = t;
    __syncthreads();
    for (int off = 1; off < 256; off <<= 1) {
        int x = (tid >= off) ? s[tid - off] : 0;
        __syncthreads();
        s[tid] += x;
        __syncthreads();
    }
    if (tid == 255) bsum[blockIdx.x] = s[255];
    int run = s[tid] - t;
#pragma unroll
    for (int c = 0; c < 8; c++) {
        int idx = base + c;
        if (idx < n) out[idx] = run;
        run += v[c];
    }
}

__global__ __launch_bounds__(256) void k_scanB(int* __restrict__ bsum, int nb) {
    __shared__ int s[256];
    const int tid = threadIdx.x;
    int v = (tid < nb) ? bsum[tid] : 0;
    s[tid] = v;
    __syncthreads();
    for (int off = 1; off < 256; off <<= 1) {
        int x = (tid >= off) ? s[tid - off] : 0;
        __syncthreads();
        s[tid] += x;
        __syncthreads();
    }
    if (tid < nb) bsum[tid] = s[tid] - v;
}

// ---- coarse scatter: tmp[pos] = (dst&511)<<17 | src  (26 bits) -------------
// global offset = sc[idx] + bsum[idx>>11]  (scanC folded in)
__global__ __launch_bounds__(256) void k_scatC(const int* __restrict__ src,
                                               const int* __restrict__ dst,
                                               const int* __restrict__ sc,
                                               const int* __restrict__ bsum,
                                               unsigned* __restrict__ tmp, int e) {
    __shared__ int cur[NCB];
    for (int i = threadIdx.x; i < NCB; i += 256) {
        size_t idx = (size_t)i * NCH + blockIdx.x;
        cur[i] = sc[idx] + bsum[idx >> 11];
    }
    __syncthreads();
    const int s = blockIdx.x * CHK, eend = min(s + CHK, e);
    for (int i = s + threadIdx.x; i < eend; i += 256) {
        int d = dst[i];
        int p = atomicAdd(&cur[d >> 9], 1);
        tmp[p] = ((unsigned)(d & 511) << 17) | (unsigned)src[i];
    }
}

// ---- per-bin (512 nodes): LDS hist + scan; emit degi/offs/dis + csr --------
__global__ __launch_bounds__(1024) void k_fill512(const unsigned* __restrict__ tmp,
                                                  const int* __restrict__ sc,
                                                  const int* __restrict__ bsum,
                                                  int* __restrict__ csr,
                                                  int* __restrict__ degi,
                                                  int* __restrict__ offs,
                                                  float* __restrict__ dis,
                                                  int n, int etotal) {
    __shared__ int cnt[512];
    __shared__ int s[512];
    __shared__ int cur[512];
    const int b = blockIdx.x, tid = threadIdx.x;
    if (tid < 512) cnt[tid] = 0;
    size_t i0 = (size_t)b * NCH;
    const int e0 = sc[i0] + bsum[i0 >> 11];
    int e1 = etotal;
    if (b + 1 < NCB) {
        size_t i1 = (size_t)(b + 1) * NCH;
        e1 = sc[i1] + bsum[i1 >> 11];
    }
    __syncthreads();
    for (int e = e0 + tid; e < e1; e += 1024)
        atomicAdd(&cnt[tmp[e] >> 17], 1);
    __syncthreads();
    int v = 0;
    if (tid < 512) { v = cnt[tid]; s[tid] = v; }
    __syncthreads();
    for (int off = 1; off < 512; off <<= 1) {
        int x = 0;
        if (tid < 512 && tid >= off) x = s[tid - off];
        __syncthreads();
        if (tid < 512) s[tid] += x;
        __syncthreads();
    }
    if (tid < 512) {
        int c = e0 + s[tid] - v;   // exclusive prefix within bin window
        cur[tid] = c;
        int node = b * 512 + tid;
        if (node < n) {
            degi[node] = v;
            offs[node] = c;
            dis[node] = rsqrtf((float)v + 1.0f);
        }
    }
    __syncthreads();
    for (int e = e0 + tid; e < e1; e += 1024) {
        unsigned pk = tmp[e];
        int p = atomicAdd(&cur[pk >> 17], 1);
        csr[p] = (int)(pk & 0x1FFFFu);
    }
}

// ---- gemm1: H1' = fp8((x @ W1) * dis[row])  (128 -> 32) --------------------
__global__ __launch_bounds__(256) void k_gemm1(const float* __restrict__ X,
                                               const float* __restrict__ W,
                                               const float* __restrict__ dis,
                                               unsigned* __restrict__ H, int n) {
    constexpr int IN = 128, ROWS = 32;
    __shared__ float sW[IN * 32];
    __shared__ float sX[ROWS][IN];
    const int tid = threadIdx.x;
    for (int i = tid; i < IN * 32; i += 256) sW[i] = W[i];
    const int row0 = blockIdx.x * ROWS;
    const float4* X4 = (const float4*)X;
    for (int i = tid; i < ROWS * 32; i += 256) {
        int r = row0 + (i >> 5);
        float4 v = make_float4(0.f, 0.f, 0.f, 0.f);
        if (r < n) v = X4[(size_t)r * 32 + (i & 31)];
        ((float4*)&sX[i >> 5][0])[i & 31] = v;
    }
    __syncthreads();
    const int lr = tid >> 3;        // local row
    const int cg = tid & 7;         // col group (4 cols)
    const int gr = row0 + lr;
    float acc[4] = {0.f, 0.f, 0.f, 0.f};
#pragma unroll 8
    for (int k = 0; k < IN; k++) {
        float xv = sX[lr][k];
#pragma unroll
        for (int c = 0; c < 4; c++)
            acc[c] = fmaf(xv, sW[k * 32 + 4 * cg + c], acc[c]);
    }
    if (gr < n) {
        float dd = dis[gr];
        H[(size_t)gr * 8 + cg] =
            pack_fp8x4(acc[0] * dd, acc[1] * dd, acc[2] * dd, acc[3] * dd);
    }
}

// ---- layer-1 pull (32-dim fp8): 8 lanes/node, 8-edge unroll ----------------
// out = fp8(relu(dis*(self+sum)+b) * dis)
__global__ __launch_bounds__(256) void k_pull2(
        const unsigned* __restrict__ Hp, const int* __restrict__ offs,
        const int* __restrict__ degi, const int* __restrict__ csr,
        const float* __restrict__ dis, const float* __restrict__ b,
        unsigned* __restrict__ A, int n) {
    const int group = threadIdx.x >> 3, j0 = threadIdx.x & 7;
    const int d = blockIdx.x * 32 + group;
    if (d >= n) return;
    float acc[4];
    set_fp8x4(Hp[(size_t)d * 8 + j0], acc);
    int e = offs[d];
    const int end = e + degi[d];
    for (; e + 7 < end; e += 8) {
        unsigned v0 = Hp[(size_t)csr[e] * 8 + j0];
        unsigned v1 = Hp[(size_t)csr[e + 1] * 8 + j0];
        unsigned v2 = Hp[(size_t)csr[e + 2] * 8 + j0];
        unsigned v3 = Hp[(size_t)csr[e + 3] * 8 + j0];
        unsigned v4 = Hp[(size_t)csr[e + 4] * 8 + j0];
        unsigned v5 = Hp[(size_t)csr[e + 5] * 8 + j0];
        unsigned v6 = Hp[(size_t)csr[e + 6] * 8 + j0];
        unsigned v7 = Hp[(size_t)csr[e + 7] * 8 + j0];
        acc_fp8x4(v0, acc); acc_fp8x4(v1, acc);
        acc_fp8x4(v2, acc); acc_fp8x4(v3, acc);
        acc_fp8x4(v4, acc); acc_fp8x4(v5, acc);
        acc_fp8x4(v6, acc); acc_fp8x4(v7, acc);
    }
    for (; e < end; e++) acc_fp8x4(Hp[(size_t)csr[e] * 8 + j0], acc);
    const float dd = dis[d];
    float r[4];
#pragma unroll
    for (int c = 0; c < 4; c++)
        r[c] = fmaxf(fmaf(acc[c], dd, b[4 * j0 + c]), 0.f) * dd;
    A[(size_t)d * 8 + j0] = pack_fp8x4(r[0], r[1], r[2], r[3]);
}

// ---- layer-2: pull(32 fp8) + fused gemm 32->48 -> fp8 padded-64 rows -------
__global__ __launch_bounds__(256) void k_pullmm32(
        const unsigned* __restrict__ Hp, const int* __restrict__ offs,
        const int* __restrict__ degi, const int* __restrict__ csr,
        const float* __restrict__ dis, const float* __restrict__ W,
        const float* __restrict__ b, unsigned* __restrict__ A, int n) {
    __shared__ float sW[32 * 48];
    __shared__ float rows[32][33];   // +1 pad: kill 8-way store conflict
    for (int i = threadIdx.x; i < 32 * 48; i += 256) sW[i] = W[i];
    const int group = threadIdx.x >> 3, j0 = threadIdx.x & 7;
    const int d = blockIdx.x * 32 + group;
    if (d < n) {
        float acc[4];
        set_fp8x4(Hp[(size_t)d * 8 + j0], acc);
        int e = offs[d];
        const int end = e + degi[d];
        for (; e + 7 < end; e += 8) {
            unsigned v0 = Hp[(size_t)csr[e] * 8 + j0];
            unsigned v1 = Hp[(size_t)csr[e + 1] * 8 + j0];
            unsigned v2 = Hp[(size_t)csr[e + 2] * 8 + j0];
            unsigned v3 = Hp[(size_t)csr[e + 3] * 8 + j0];
            unsigned v4 = Hp[(size_t)csr[e + 4] * 8 + j0];
            unsigned v5 = Hp[(size_t)csr[e + 5] * 8 + j0];
            unsigned v6 = Hp[(size_t)csr[e + 6] * 8 + j0];
            unsigned v7 = Hp[(size_t)csr[e + 7] * 8 + j0];
            acc_fp8x4(v0, acc); acc_fp8x4(v1, acc);
            acc_fp8x4(v2, acc); acc_fp8x4(v3, acc);
            acc_fp8x4(v4, acc); acc_fp8x4(v5, acc);
            acc_fp8x4(v6, acc); acc_fp8x4(v7, acc);
        }
        for (; e < end; e++) acc_fp8x4(Hp[(size_t)csr[e] * 8 + j0], acc);
        const float dd = dis[d];
#pragma unroll
        for (int c = 0; c < 4; c++) rows[group][4 * j0 + c] = acc[c] * dd;
    }
    __syncthreads();
    const int row0 = blockIdx.x * 32;
    // 32 rows x 16 uint-groups (12 real + 4 pad): compute 4 cols + pack inline
    for (int u = threadIdx.x; u < 32 * 16; u += 256) {
        int nl = u >> 4, cg = u & 15;
        int gr = row0 + nl;
        if (gr < n) {
            unsigned p = 0;
            if (cg < 12) {
                float dd2 = dis[gr];
                float r[4];
#pragma unroll
                for (int c = 0; c < 4; c++) {
                    float s = b[4 * cg + c];
#pragma unroll
                    for (int k = 0; k < 32; k++)
                        s = fmaf(rows[nl][k], sW[k * 48 + 4 * cg + c], s);
                    r[c] = fmaxf(s, 0.f) * dd2;
                }
                p = pack_fp8x4(r[0], r[1], r[2], r[3]);
            }
            A[(size_t)gr * 16 + cg] = p;
        }
    }
}

// ---- layer-3: pull(48 fp8, 64B rows) + fused gemm 48->64 -> A3 fp16 --------
__global__ __launch_bounds__(256) void k_pullmm48(
        const uint2* __restrict__ Hp, const int* __restrict__ offs,
        const int* __restrict__ degi, const int* __restrict__ csr,
        const float* __restrict__ dis, const float* __restrict__ W,
        const float* __restrict__ b, __half* __restrict__ A, int n) {
    __shared__ float sW[48 * 64];
    __shared__ float rows[32][50];   // stride 50: spread store banks
    for (int i = threadIdx.x; i < 48 * 64; i += 256) sW[i] = W[i];
    const int group = threadIdx.x >> 3, j0 = threadIdx.x & 7;
    const int d = blockIdx.x * 32 + group;
    if (d < n) {
        float acc[8];
        uint2 sv = Hp[(size_t)d * 8 + j0];
        set_fp8x4(sv.x, acc); set_fp8x4(sv.y, acc + 4);
        int e = offs[d];
        const int end = e + degi[d];
        for (; e + 7 < end; e += 8) {
            uint2 v0 = Hp[(size_t)csr[e] * 8 + j0];
            uint2 v1 = Hp[(size_t)csr[e + 1] * 8 + j0];
            uint2 v2 = Hp[(size_t)csr[e + 2] * 8 + j0];
            uint2 v3 = Hp[(size_t)csr[e + 3] * 8 + j0];
            uint2 v4 = Hp[(size_t)csr[e + 4] * 8 + j0];
            uint2 v5 = Hp[(size_t)csr[e + 5] * 8 + j0];
            uint2 v6 = Hp[(size_t)csr[e + 6] * 8 + j0];
            uint2 v7 = Hp[(size_t)csr[e + 7] * 8 + j0];
            acc_fp8x4(v0.x, acc); acc_fp8x4(v0.y, acc + 4);
            acc_fp8x4(v1.x, acc); acc_fp8x4(v1.y, acc + 4);
            acc_fp8x4(v2.x, acc); acc_fp8x4(v2.y, acc + 4);
            acc_fp8x4(v3.x, acc); acc_fp8x4(v3.y, acc + 4);
            acc_fp8x4(v4.x, acc); acc_fp8x4(v4.y, acc + 4);
            acc_fp8x4(v5.x, acc); acc_fp8x4(v5.y, acc + 4);
            acc_fp8x4(v6.x, acc); acc_fp8x4(v6.y, acc + 4);
            acc_fp8x4(v7.x, acc); acc_fp8x4(v7.y, acc + 4);
        }
        for (; e < end; e++) {
            uint2 v = Hp[(size_t)csr[e] * 8 + j0];
            acc_fp8x4(v.x, acc); acc_fp8x4(v.y, acc + 4);
        }
        const float dd = dis[d];
        if (j0 < 6) {   // j0>=6 holds pad bytes 48..63
#pragma unroll
            for (int c = 0; c < 8; c++) rows[group][8 * j0 + c] = acc[c] * dd;
        }
    }
    __syncthreads();
    const int row0 = blockIdx.x * 32;
#pragma unroll
    for (int o = 0; o < 8; o++) {
        int idx = o * 256 + threadIdx.x;
        int nl = idx >> 6, col = idx & 63;
        int gr = row0 + nl;
        if (gr < n) {
            float s = b[col];
#pragma unroll
            for (int k = 0; k < 48; k++)
                s = fmaf(rows[nl][k], sW[k * 64 + col], s);
            A[(size_t)gr * 64 + col] = __float2half(s);
        }
    }
}

// ---- fused: graph bounds (binary search) + mean-pool + MLP head + softmax --
__global__ __launch_bounds__(256) void k_poolhead(
        const __half* __restrict__ A3, const int* __restrict__ batch,
        const float* __restrict__ f1w, const float* __restrict__ f1b,
        const float* __restrict__ f2w, const float* __restrict__ f2b,
        float* __restrict__ out, int n, int ngr) {
    const int g = blockIdx.x;
    __shared__ int sb[2];
    if (threadIdx.x < 2) {
        int target = g + threadIdx.x;
        int lo = 0, hi = n;
        while (lo < hi) {
            int mid = (lo + hi) >> 1;
            if (batch[mid] < target) lo = mid + 1; else hi = mid;
        }
        sb[threadIdx.x] = lo;
    }
    __syncthreads();
    const int s = sb[0], e = sb[1];
    const int j = threadIdx.x & 63, rl = threadIdx.x >> 6;
    float sum = 0.f;
    for (int node = s + rl; node < e; node += 4)
        sum += fmaxf(__half2float(A3[(size_t)node * 64 + j]), 0.f);
    __shared__ float red[4][64];
    __shared__ float p[64], z[32], lg[16];
    red[rl][j] = sum;
    __syncthreads();
    if (rl == 0)
        p[j] = (red[0][j] + red[1][j] + red[2][j] + red[3][j]) /
               fmaxf((float)(e - s), 1.f);
    __syncthreads();
    const int t = threadIdx.x;
    if (t < 32) {
        float acc = f1b[t];
        for (int k = 0; k < 64; k++) acc = fmaf(p[k], f1w[k * 32 + t], acc);
        z[t] = fmaxf(acc, 0.f);
    }
    __syncthreads();
    if (t < 16) {
        float acc = f2b[t];
        for (int k = 0; k < 32; k++) acc = fmaf(z[k], f2w[k * 16 + t], acc);
        lg[t] = acc;
    }
    __syncthreads();
    if (t < 16) {
        float m = lg[0];
        for (int i = 1; i < 16; i++) m = fmaxf(m, lg[i]);
        float sden = 0.f;
        for (int i = 0; i < 16; i++) sden += expf(lg[i] - m);
        out[g * 16 + t] = expf(lg[t] - m) / sden;
    }
}

extern "C" void kernel_launch(void* const* d_in, const int* in_sizes, int n_in,
                              void* d_out, int out_size, void* d_ws, size_t ws_size,
                              hipStream_t stream) {
    (void)in_sizes; (void)n_in; (void)out_size; (void)ws_size;
    const float* x     = (const float*)d_in[0];
    const int*   ei    = (const int*)d_in[1];
    const int*   batch = (const int*)d_in[2];
    const float* W1 = (const float*)d_in[3];
    const float* b1 = (const float*)d_in[4];
    const float* W2 = (const float*)d_in[5];  const float* b2 = (const float*)d_in[6];
    const float* W3 = (const float*)d_in[7];  const float* b3 = (const float*)d_in[8];
    const float* f1w = (const float*)d_in[9]; const float* f1b = (const float*)d_in[10];
    const float* f2w = (const float*)d_in[11];const float* f2b = (const float*)d_in[12];
    float* out = (float*)d_out;

    const int* src = ei;
    const int* dst = ei + NE;

    // Workspace (~41 MB):
    //   tmp uint[NE] (12.8MB)  aliased with  A3 fp16[NN*64] (12.8MB)
    //   H1 fp8[NN*32] (3.2MB), H2 fp8[NN*32] (3.2MB), H3 fp8[NN*64] (6.4MB)
    float* ws = (float*)d_ws;
    size_t o = 0;
    float* dis    = ws + o; o += NN;
    int*   degi   = (int*)(ws + o); o += NN;
    int*   offs   = (int*)(ws + o); o += NN;
    int*   cntC   = (int*)(ws + o); o += 76640;       // NCNT padded to /16
    int*   sc     = (int*)(ws + o); o += 76640;
    int*   bsum   = (int*)(ws + o); o += 48;
    int*   csr    = (int*)(ws + o); o += NE;
    unsigned* TA  = (unsigned*)(ws + o); o += NE;     // tmp | A3
    unsigned* H1  = (unsigned*)(ws + o); o += NN * 8;
    unsigned* H2  = (unsigned*)(ws + o); o += NN * 8;
    unsigned* H3  = (unsigned*)(ws + o); o += NN * 16;

    unsigned* tmp = TA;
    __half*   A3  = (__half*)TA;

    // CSR build: coarse counting sort (196 bins x 512 nodes) + in-LDS sub-sort
    k_histC<<<NCH, 256, 0, stream>>>(dst, cntC, NE);
    k_scanA<<<NSB, 256, 0, stream>>>(cntC, sc, bsum, NCNT);
    k_scanB<<<1, 256, 0, stream>>>(bsum, NSB);
    k_scatC<<<NCH, 256, 0, stream>>>(src, dst, sc, bsum, tmp, NE);
    k_fill512<<<NCB, 1024, 0, stream>>>(tmp, sc, bsum, csr, degi, offs, dis, NN, NE);

    const int PGRID = (NN + 31) / 32;  // 3125

    // Layer 1: transform-first GEMM (128->32) -> fp8 H1; pull -> fp8 H2
    k_gemm1<<<(NN + 31) / 32, 256, 0, stream>>>(x, W1, dis, H1, NN);
    k_pull2<<<PGRID, 256, 0, stream>>>(H1, offs, degi, csr, dis, b1, H2, NN);

    // Layer 2: pull(32 fp8) + fused gemm 32->48 -> fp8 H3 (64B rows)
    k_pullmm32<<<PGRID, 256, 0, stream>>>(H2, offs, degi, csr, dis, W2, b2, H3, NN);

    // Layer 3: pull(48 fp8) + fused gemm 48->64 -> A3 fp16
    k_pullmm48<<<PGRID, 256, 0, stream>>>(
        (const uint2*)H3, offs, degi, csr, dis, W3, b3, A3, NN);

    // Fused bounds + pool + head
    k_poolhead<<<NG, 256, 0, stream>>>(A3, batch, f1w, f1b, f2w, f2b, out, NN, NG);
}

// Round 13
// 350.465 us; speedup vs baseline: 1.1290x; 1.0486x over previous
//
#include <hip/hip_runtime.h>
#include <hip/hip_fp16.h>

static constexpr int NN = 100000;
static constexpr int NE = 3200000;
static constexpr int NG = 512;
static constexpr int NCB = 196;                       // coarse bins: 512 nodes (dst>>9)
static constexpr int CHK = 8192;
static constexpr int NCH = (NE + CHK - 1) / CHK;      // 391 chunks
static constexpr int NCNT = NCB * NCH;                // 76636 count cells
static constexpr int SCAN_BLK = 2048;
static constexpr int NSB = (NCNT + SCAN_BLK - 1) / SCAN_BLK;  // 38

// ---- fp8 e4m3 pack/unpack via gfx950 hardware converts ---------------------
typedef float f32x2 __attribute__((ext_vector_type(2)));

__device__ __forceinline__ void acc_fp8x4(unsigned v, float* a) {
    f32x2 lo = __builtin_amdgcn_cvt_pk_f32_fp8((int)v, false);
    f32x2 hi = __builtin_amdgcn_cvt_pk_f32_fp8((int)v, true);
    a[0] += lo.x; a[1] += lo.y; a[2] += hi.x; a[3] += hi.y;
}
__device__ __forceinline__ void set_fp8x4(unsigned v, float* a) {
    f32x2 lo = __builtin_amdgcn_cvt_pk_f32_fp8((int)v, false);
    f32x2 hi = __builtin_amdgcn_cvt_pk_f32_fp8((int)v, true);
    a[0] = lo.x; a[1] = lo.y; a[2] = hi.x; a[3] = hi.y;
}
__device__ __forceinline__ unsigned pack_fp8x4(float a, float b, float c, float d) {
    int p = __builtin_amdgcn_cvt_pk_fp8_f32(a, b, 0, false);
    p = __builtin_amdgcn_cvt_pk_fp8_f32(c, d, p, true);
    return (unsigned)p;
}

// ---- per-chunk coarse histogram (int4 dst stream): cntC[bin*NCH + chunk] ---
__global__ __launch_bounds__(256) void k_histC(const int4* __restrict__ dst4,
                                               int* __restrict__ cntC, int e4) {
    __shared__ int h[NCB];
    for (int i = threadIdx.x; i < NCB; i += 256) h[i] = 0;
    __syncthreads();
    const int s4 = blockIdx.x * (CHK / 4), e4end = min(s4 + CHK / 4, e4);
    for (int i = s4 + threadIdx.x; i < e4end; i += 256) {
        int4 d = dst4[i];
        atomicAdd(&h[d.x >> 9], 1);
        atomicAdd(&h[d.y >> 9], 1);
        atomicAdd(&h[d.z >> 9], 1);
        atomicAdd(&h[d.w >> 9], 1);
    }
    __syncthreads();
    for (int i = threadIdx.x; i < NCB; i += 256)
        cntC[(size_t)i * NCH + blockIdx.x] = h[i];
}

// ---- 2-kernel exclusive scan (block-local + bsum scan; add folded later) ---
__global__ __launch_bounds__(256) void k_scanA(const int* __restrict__ in,
                                               int* __restrict__ out,
                                               int* __restrict__ bsum, int n) {
    __shared__ int s[256];
    const int tid = threadIdx.x;
    const int base = blockIdx.x * SCAN_BLK + tid * 8;
    int v[8], t = 0;
#pragma unroll
    for (int c = 0; c < 8; c++) {
        int idx = base + c;
        v[c] = (idx < n) ? in[idx] : 0;
        t += v[c];
    }
    s[tid] = t;
    __syncthreads();
    for (int off = 1; off < 256; off <<= 1) {
        int x = (tid >= off) ? s[tid - off] : 0;
        __syncthreads();
        s[tid] += x;
        __syncthreads();
    }
    if (tid == 255) bsum[blockIdx.x] = s[255];
    int run = s[tid] - t;
#pragma unroll
    for (int c = 0; c < 8; c++) {
        int idx = base + c;
        if (idx < n) out[idx] = run;
        run += v[c];
    }
}

__global__ __launch_bounds__(256) void k_scanB(int* __restrict__ bsum, int nb) {
    __shared__ int s[256];
    const int tid = threadIdx.x;
    int v = (tid < nb) ? bsum[tid] : 0;
    s[tid] = v;
    __syncthreads();
    for (int off = 1; off < 256; off <<= 1) {
        int x = (tid >= off) ? s[tid - off] : 0;
        __syncthreads();
        s[tid] += x;
        __syncthreads();
    }
    if (tid < nb) bsum[tid] = s[tid] - v;
}

// ---- coarse scatter (int4 streams): tmp[pos] = (dst&511)<<17 | src ---------
// global offset = sc[idx] + bsum[idx>>11]  (scanC folded in)
__global__ __launch_bounds__(256) void k_scatC(const int4* __restrict__ src4,
                                               const int4* __restrict__ dst4,
                                               const int* __restrict__ sc,
                                               const int* __restrict__ bsum,
                                               unsigned* __restrict__ tmp, int e4) {
    __shared__ int cur[NCB];
    for (int i = threadIdx.x; i < NCB; i += 256) {
        size_t idx = (size_t)i * NCH + blockIdx.x;
        cur[i] = sc[idx] + bsum[idx >> 11];
    }
    __syncthreads();
    const int s4 = blockIdx.x * (CHK / 4), e4end = min(s4 + CHK / 4, e4);
    for (int i = s4 + threadIdx.x; i < e4end; i += 256) {
        int4 d = dst4[i];
        int4 sv = src4[i];
        int p0 = atomicAdd(&cur[d.x >> 9], 1);
        tmp[p0] = ((unsigned)(d.x & 511) << 17) | (unsigned)sv.x;
        int p1 = atomicAdd(&cur[d.y >> 9], 1);
        tmp[p1] = ((unsigned)(d.y & 511) << 17) | (unsigned)sv.y;
        int p2 = atomicAdd(&cur[d.z >> 9], 1);
        tmp[p2] = ((unsigned)(d.z & 511) << 17) | (unsigned)sv.z;
        int p3 = atomicAdd(&cur[d.w >> 9], 1);
        tmp[p3] = ((unsigned)(d.w & 511) << 17) | (unsigned)sv.w;
    }
}

// ---- per-bin (512 nodes): LDS hist + scan; emit degi/offs/dis + csr --------
__global__ __launch_bounds__(1024) void k_fill512(const unsigned* __restrict__ tmp,
                                                  const int* __restrict__ sc,
                                                  const int* __restrict__ bsum,
                                                  int* __restrict__ csr,
                                                  int* __restrict__ degi,
                                                  int* __restrict__ offs,
                                                  float* __restrict__ dis,
                                                  int n, int etotal) {
    __shared__ int cnt[512];
    __shared__ int s[512];
    __shared__ int cur[512];
    const int b = blockIdx.x, tid = threadIdx.x;
    if (tid < 512) cnt[tid] = 0;
    size_t i0 = (size_t)b * NCH;
    const int e0 = sc[i0] + bsum[i0 >> 11];
    int e1 = etotal;
    if (b + 1 < NCB) {
        size_t i1 = (size_t)(b + 1) * NCH;
        e1 = sc[i1] + bsum[i1 >> 11];
    }
    __syncthreads();
    for (int e = e0 + tid; e < e1; e += 1024)
        atomicAdd(&cnt[tmp[e] >> 17], 1);
    __syncthreads();
    int v = 0;
    if (tid < 512) { v = cnt[tid]; s[tid] = v; }
    __syncthreads();
    for (int off = 1; off < 512; off <<= 1) {
        int x = 0;
        if (tid < 512 && tid >= off) x = s[tid - off];
        __syncthreads();
        if (tid < 512) s[tid] += x;
        __syncthreads();
    }
    if (tid < 512) {
        int c = e0 + s[tid] - v;   // exclusive prefix within bin window
        cur[tid] = c;
        int node = b * 512 + tid;
        if (node < n) {
            degi[node] = v;
            offs[node] = c;
            dis[node] = rsqrtf((float)v + 1.0f);
        }
    }
    __syncthreads();
    for (int e = e0 + tid; e < e1; e += 1024) {
        unsigned pk = tmp[e];
        int p = atomicAdd(&cur[pk >> 17], 1);
        csr[p] = (int)(pk & 0x1FFFFu);
    }
}

// ---- gemm1: H1' = fp8((x @ W1) * dis[row])  (128 -> 32) --------------------
__global__ __launch_bounds__(256) void k_gemm1(const float* __restrict__ X,
                                               const float* __restrict__ W,
                                               const float* __restrict__ dis,
                                               unsigned* __restrict__ H, int n) {
    constexpr int IN = 128, ROWS = 32;
    __shared__ float sW[IN * 32];
    __shared__ float sX[ROWS][IN];
    const int tid = threadIdx.x;
    for (int i = tid; i < IN * 32; i += 256) sW[i] = W[i];
    const int row0 = blockIdx.x * ROWS;
    const float4* X4 = (const float4*)X;
    for (int i = tid; i < ROWS * 32; i += 256) {
        int r = row0 + (i >> 5);
        float4 v = make_float4(0.f, 0.f, 0.f, 0.f);
        if (r < n) v = X4[(size_t)r * 32 + (i & 31)];
        ((float4*)&sX[i >> 5][0])[i & 31] = v;
    }
    __syncthreads();
    const int lr = tid >> 3;        // local row
    const int cg = tid & 7;         // col group (4 cols)
    const int gr = row0 + lr;
    float acc[4] = {0.f, 0.f, 0.f, 0.f};
#pragma unroll 8
    for (int k = 0; k < IN; k++) {
        float xv = sX[lr][k];
#pragma unroll
        for (int c = 0; c < 4; c++)
            acc[c] = fmaf(xv, sW[k * 32 + 4 * cg + c], acc[c]);
    }
    if (gr < n) {
        float dd = dis[gr];
        H[(size_t)gr * 8 + cg] =
            pack_fp8x4(acc[0] * dd, acc[1] * dd, acc[2] * dd, acc[3] * dd);
    }
}

// ---- layer-1 pull (32-dim fp8): 8 lanes/node, 8-edge unroll ----------------
// out = fp8(relu(dis*(self+sum)+b) * dis)
__global__ __launch_bounds__(256) void k_pull2(
        const unsigned* __restrict__ Hp, const int* __restrict__ offs,
        const int* __restrict__ degi, const int* __restrict__ csr,
        const float* __restrict__ dis, const float* __restrict__ b,
        unsigned* __restrict__ A, int n) {
    const int group = threadIdx.x >> 3, j0 = threadIdx.x & 7;
    const int d = blockIdx.x * 32 + group;
    if (d >= n) return;
    float acc[4];
    set_fp8x4(Hp[(size_t)d * 8 + j0], acc);
    int e = offs[d];
    const int end = e + degi[d];
    for (; e + 7 < end; e += 8) {
        unsigned v0 = Hp[(size_t)csr[e] * 8 + j0];
        unsigned v1 = Hp[(size_t)csr[e + 1] * 8 + j0];
        unsigned v2 = Hp[(size_t)csr[e + 2] * 8 + j0];
        unsigned v3 = Hp[(size_t)csr[e + 3] * 8 + j0];
        unsigned v4 = Hp[(size_t)csr[e + 4] * 8 + j0];
        unsigned v5 = Hp[(size_t)csr[e + 5] * 8 + j0];
        unsigned v6 = Hp[(size_t)csr[e + 6] * 8 + j0];
        unsigned v7 = Hp[(size_t)csr[e + 7] * 8 + j0];
        acc_fp8x4(v0, acc); acc_fp8x4(v1, acc);
        acc_fp8x4(v2, acc); acc_fp8x4(v3, acc);
        acc_fp8x4(v4, acc); acc_fp8x4(v5, acc);
        acc_fp8x4(v6, acc); acc_fp8x4(v7, acc);
    }
    for (; e < end; e++) acc_fp8x4(Hp[(size_t)csr[e] * 8 + j0], acc);
    const float dd = dis[d];
    float r[4];
#pragma unroll
    for (int c = 0; c < 4; c++)
        r[c] = fmaxf(fmaf(acc[c], dd, b[4 * j0 + c]), 0.f) * dd;
    A[(size_t)d * 8 + j0] = pack_fp8x4(r[0], r[1], r[2], r[3]);
}

// ---- layer-2: pull(32 fp8) + fused gemm 32->48 -> fp8 padded-64 rows -------
__global__ __launch_bounds__(256) void k_pullmm32(
        const unsigned* __restrict__ Hp, const int* __restrict__ offs,
        const int* __restrict__ degi, const int* __restrict__ csr,
        const float* __restrict__ dis, const float* __restrict__ W,
        const float* __restrict__ b, unsigned* __restrict__ A, int n) {
    __shared__ float sW[32 * 48];
    __shared__ float rows[32][33];   // +1 pad: kill 8-way store conflict
    for (int i = threadIdx.x; i < 32 * 48; i += 256) sW[i] = W[i];
    const int group = threadIdx.x >> 3, j0 = threadIdx.x & 7;
    const int d = blockIdx.x * 32 + group;
    if (d < n) {
        float acc[4];
        set_fp8x4(Hp[(size_t)d * 8 + j0], acc);
        int e = offs[d];
        const int end = e + degi[d];
        for (; e + 7 < end; e += 8) {
            unsigned v0 = Hp[(size_t)csr[e] * 8 + j0];
            unsigned v1 = Hp[(size_t)csr[e + 1] * 8 + j0];
            unsigned v2 = Hp[(size_t)csr[e + 2] * 8 + j0];
            unsigned v3 = Hp[(size_t)csr[e + 3] * 8 + j0];
            unsigned v4 = Hp[(size_t)csr[e + 4] * 8 + j0];
            unsigned v5 = Hp[(size_t)csr[e + 5] * 8 + j0];
            unsigned v6 = Hp[(size_t)csr[e + 6] * 8 + j0];
            unsigned v7 = Hp[(size_t)csr[e + 7] * 8 + j0];
            acc_fp8x4(v0, acc); acc_fp8x4(v1, acc);
            acc_fp8x4(v2, acc); acc_fp8x4(v3, acc);
            acc_fp8x4(v4, acc); acc_fp8x4(v5, acc);
            acc_fp8x4(v6, acc); acc_fp8x4(v7, acc);
        }
        for (; e < end; e++) acc_fp8x4(Hp[(size_t)csr[e] * 8 + j0], acc);
        const float dd = dis[d];
#pragma unroll
        for (int c = 0; c < 4; c++) rows[group][4 * j0 + c] = acc[c] * dd;
    }
    __syncthreads();
    const int row0 = blockIdx.x * 32;
    // 32 rows x 16 uint-groups (12 real + 4 pad): compute 4 cols + pack inline
    for (int u = threadIdx.x; u < 32 * 16; u += 256) {
        int nl = u >> 4, cg = u & 15;
        int gr = row0 + nl;
        if (gr < n) {
            unsigned p = 0;
            if (cg < 12) {
                float dd2 = dis[gr];
                float r[4];
#pragma unroll
                for (int c = 0; c < 4; c++) {
                    float s = b[4 * cg + c];
#pragma unroll
                    for (int k = 0; k < 32; k++)
                        s = fmaf(rows[nl][k], sW[k * 48 + 4 * cg + c], s);
                    r[c] = fmaxf(s, 0.f) * dd2;
                }
                p = pack_fp8x4(r[0], r[1], r[2], r[3]);
            }
            A[(size_t)gr * 16 + cg] = p;
        }
    }
}

// ---- layer-3: pull(48 fp8, 64B rows) + fused gemm 48->64 -> A3 fp16 --------
__global__ __launch_bounds__(256) void k_pullmm48(
        const uint2* __restrict__ Hp, const int* __restrict__ offs,
        const int* __restrict__ degi, const int* __restrict__ csr,
        const float* __restrict__ dis, const float* __restrict__ W,
        const float* __restrict__ b, __half* __restrict__ A, int n) {
    __shared__ float sW[48 * 64];
    __shared__ float rows[32][48];   // R10 config (measured fastest)
    for (int i = threadIdx.x; i < 48 * 64; i += 256) sW[i] = W[i];
    const int group = threadIdx.x >> 3, j0 = threadIdx.x & 7;
    const int d = blockIdx.x * 32 + group;
    if (d < n) {
        float acc[8];
        uint2 sv = Hp[(size_t)d * 8 + j0];
        set_fp8x4(sv.x, acc); set_fp8x4(sv.y, acc + 4);
        int e = offs[d];
        const int end = e + degi[d];
        for (; e + 7 < end; e += 8) {
            uint2 v0 = Hp[(size_t)csr[e] * 8 + j0];
            uint2 v1 = Hp[(size_t)csr[e + 1] * 8 + j0];
            uint2 v2 = Hp[(size_t)csr[e + 2] * 8 + j0];
            uint2 v3 = Hp[(size_t)csr[e + 3] * 8 + j0];
            uint2 v4 = Hp[(size_t)csr[e + 4] * 8 + j0];
            uint2 v5 = Hp[(size_t)csr[e + 5] * 8 + j0];
            uint2 v6 = Hp[(size_t)csr[e + 6] * 8 + j0];
            uint2 v7 = Hp[(size_t)csr[e + 7] * 8 + j0];
            acc_fp8x4(v0.x, acc); acc_fp8x4(v0.y, acc + 4);
            acc_fp8x4(v1.x, acc); acc_fp8x4(v1.y, acc + 4);
            acc_fp8x4(v2.x, acc); acc_fp8x4(v2.y, acc + 4);
            acc_fp8x4(v3.x, acc); acc_fp8x4(v3.y, acc + 4);
            acc_fp8x4(v4.x, acc); acc_fp8x4(v4.y, acc + 4);
            acc_fp8x4(v5.x, acc); acc_fp8x4(v5.y, acc + 4);
            acc_fp8x4(v6.x, acc); acc_fp8x4(v6.y, acc + 4);
            acc_fp8x4(v7.x, acc); acc_fp8x4(v7.y, acc + 4);
        }
        for (; e < end; e++) {
            uint2 v = Hp[(size_t)csr[e] * 8 + j0];
            acc_fp8x4(v.x, acc); acc_fp8x4(v.y, acc + 4);
        }
        const float dd = dis[d];
        if (j0 < 6) {   // j0>=6 holds pad bytes 48..63
#pragma unroll
            for (int c = 0; c < 8; c++) rows[group][8 * j0 + c] = acc[c] * dd;
        }
    }
    __syncthreads();
    const int row0 = blockIdx.x * 32;
#pragma unroll
    for (int o = 0; o < 8; o++) {
        int idx = o * 256 + threadIdx.x;
        int nl = idx >> 6, col = idx & 63;
        int gr = row0 + nl;
        if (gr < n) {
            float s = b[col];
#pragma unroll
            for (int k = 0; k < 48; k++)
                s = fmaf(rows[nl][k], sW[k * 64 + col], s);
            A[(size_t)gr * 64 + col] = __float2half(s);
        }
    }
}

// ---- fused: graph bounds (binary search) + mean-pool + MLP head + softmax --
__global__ __launch_bounds__(256) void k_poolhead(
        const __half* __restrict__ A3, const int* __restrict__ batch,
        const float* __restrict__ f1w, const float* __restrict__ f1b,
        const float* __restrict__ f2w, const float* __restrict__ f2b,
        float* __restrict__ out, int n, int ngr) {
    const int g = blockIdx.x;
    __shared__ int sb[2];
    if (threadIdx.x < 2) {
        int target = g + threadIdx.x;
        int lo = 0, hi = n;
        while (lo < hi) {
            int mid = (lo + hi) >> 1;
            if (batch[mid] < target) lo = mid + 1; else hi = mid;
        }
        sb[threadIdx.x] = lo;
    }
    __syncthreads();
    const int s = sb[0], e = sb[1];
    const int j = threadIdx.x & 63, rl = threadIdx.x >> 6;
    float sum = 0.f;
    for (int node = s + rl; node < e; node += 4)
        sum += fmaxf(__half2float(A3[(size_t)node * 64 + j]), 0.f);
    __shared__ float red[4][64];
    __shared__ float p[64], z[32], lg[16];
    red[rl][j] = sum;
    __syncthreads();
    if (rl == 0)
        p[j] = (red[0][j] + red[1][j] + red[2][j] + red[3][j]) /
               fmaxf((float)(e - s), 1.f);
    __syncthreads();
    const int t = threadIdx.x;
    if (t < 32) {
        float acc = f1b[t];
        for (int k = 0; k < 64; k++) acc = fmaf(p[k], f1w[k * 32 + t], acc);
        z[t] = fmaxf(acc, 0.f);
    }
    __syncthreads();
    if (t < 16) {
        float acc = f2b[t];
        for (int k = 0; k < 32; k++) acc = fmaf(z[k], f2w[k * 16 + t], acc);
        lg[t] = acc;
    }
    __syncthreads();
    if (t < 16) {
        float m = lg[0];
        for (int i = 1; i < 16; i++) m = fmaxf(m, lg[i]);
        float sden = 0.f;
        for (int i = 0; i < 16; i++) sden += expf(lg[i] - m);
        out[g * 16 + t] = expf(lg[t] - m) / sden;
    }
}

extern "C" void kernel_launch(void* const* d_in, const int* in_sizes, int n_in,
                              void* d_out, int out_size, void* d_ws, size_t ws_size,
                              hipStream_t stream) {
    (void)in_sizes; (void)n_in; (void)out_size; (void)ws_size;
    const float* x     = (const float*)d_in[0];
    const int*   ei    = (const int*)d_in[1];
    const int*   batch = (const int*)d_in[2];
    const float* W1 = (const float*)d_in[3];
    const float* b1 = (const float*)d_in[4];
    const float* W2 = (const float*)d_in[5];  const float* b2 = (const float*)d_in[6];
    const float* W3 = (const float*)d_in[7];  const float* b3 = (const float*)d_in[8];
    const float* f1w = (const float*)d_in[9]; const float* f1b = (const float*)d_in[10];
    const float* f2w = (const float*)d_in[11];const float* f2b = (const float*)d_in[12];
    float* out = (float*)d_out;

    const int* src = ei;
    const int* dst = ei + NE;

    // Workspace (~41 MB):
    //   tmp uint[NE] (12.8MB)  aliased with  A3 fp16[NN*64] (12.8MB)
    //   H1 fp8[NN*32] (3.2MB), H2 fp8[NN*32] (3.2MB), H3 fp8[NN*64] (6.4MB)
    float* ws = (float*)d_ws;
    size_t o = 0;
    float* dis    = ws + o; o += NN;
    int*   degi   = (int*)(ws + o); o += NN;
    int*   offs   = (int*)(ws + o); o += NN;
    int*   cntC   = (int*)(ws + o); o += 76640;       // NCNT padded to /16
    int*   sc     = (int*)(ws + o); o += 76640;
    int*   bsum   = (int*)(ws + o); o += 48;
    int*   csr    = (int*)(ws + o); o += NE;
    unsigned* TA  = (unsigned*)(ws + o); o += NE;     // tmp | A3
    unsigned* H1  = (unsigned*)(ws + o); o += NN * 8;
    unsigned* H2  = (unsigned*)(ws + o); o += NN * 8;
    unsigned* H3  = (unsigned*)(ws + o); o += NN * 16;

    unsigned* tmp = (unsigned*)TA;
    __half*   A3  = (__half*)TA;

    // CSR build: coarse counting sort (196 bins x 512 nodes) + in-LDS sub-sort
    k_histC<<<NCH, 256, 0, stream>>>((const int4*)dst, cntC, NE / 4);
    k_scanA<<<NSB, 256, 0, stream>>>(cntC, sc, bsum, NCNT);
    k_scanB<<<1, 256, 0, stream>>>(bsum, NSB);
    k_scatC<<<NCH, 256, 0, stream>>>((const int4*)src, (const int4*)dst,
                                     sc, bsum, tmp, NE / 4);
    k_fill512<<<NCB, 1024, 0, stream>>>(tmp, sc, bsum, csr, degi, offs, dis, NN, NE);

    const int PGRID = (NN + 31) / 32;  // 3125

    // Layer 1: transform-first GEMM (128->32) -> fp8 H1; pull -> fp8 H2
    k_gemm1<<<(NN + 31) / 32, 256, 0, stream>>>(x, W1, dis, H1, NN);
    k_pull2<<<PGRID, 256, 0, stream>>>(H1, offs, degi, csr, dis, b1, H2, NN);

    // Layer 2: pull(32 fp8) + fused gemm 32->48 -> fp8 H3 (64B rows)
    k_pullmm32<<<PGRID, 256, 0, stream>>>(H2, offs, degi, csr, dis, W2, b2, H3, NN);

    // Layer 3: pull(48 fp8) + fused gemm 48->64 -> A3 fp16
    k_pullmm48<<<PGRID, 256, 0, stream>>>(
        (const uint2*)H3, offs, degi, csr, dis, W3, b3, A3, NN);

    // Fused bounds + pool + head
    k_poolhead<<<NG, 256, 0, stream>>>(A3, batch, f1w, f1b, f2w, f2b, out, NN, NG);
}